// Round 10
// baseline (109.688 us; speedup 1.0000x reference)
//
#include <hip/hip_runtime.h>
#include <math.h>

#define NB 4096

// ---- workspace layout ----
// ints:
#define LEAFo  0               // 3 barriers * 8 leaves * 32 ints (128B spacing)
#define MASTo  768             // 3 * 32
#define RELo   864             // 8 * 32 spread release lines
#define GHo    1120            // 4*4096 histogram
#define GCNTo  17504           // 4*4096 scatter counters
#define MEMSET_BYTES 135552    // 33888 ints
// floats:
#define Do     33888           // B*4096 (block-local)
#define VGo    50272           // B*4096*64
#define ASo    1098848         // sorted a
#define PERMo  1115232         // int
#define BSTo   1131616         // int, bucket starts
#define Po     1148000         // chunk partials [b][64ch][192]
#define PSEAo  1197152         // [b][64]
#define PSAo   1197408         // [b][64]

__device__ __forceinline__ void gst(float* p, float v) {
    __hip_atomic_store(p, v, __ATOMIC_RELAXED, __HIP_MEMORY_SCOPE_AGENT);
}
__device__ __forceinline__ void gsti(int* p, int v) {
    __hip_atomic_store(p, v, __ATOMIC_RELAXED, __HIP_MEMORY_SCOPE_AGENT);
}

__device__ __forceinline__ int bucket_of(float v) {
    int k = (int)((v + 16.0f) * 128.0f);
    k = k < 0 ? 0 : k;
    k = k > (NB - 1) ? (NB - 1) : k;
    return k;
}

// Tree-arrival barrier (validated R9): 32 contenders/leaf, 8 leaves/master,
// release on 8 spread lines.
__device__ __forceinline__ void gbar(int* wsi, int idx) {
    __syncthreads();
    if (threadIdx.x == 0) {
        int leaf = blockIdx.x & 7;
        bool bcast = false;
        int old = __hip_atomic_fetch_add(wsi + LEAFo + (idx * 8 + leaf) * 32, 1,
                                         __ATOMIC_RELAXED, __HIP_MEMORY_SCOPE_AGENT);
        if (old == 31) {
            int m = __hip_atomic_fetch_add(wsi + MASTo + idx * 32, 1,
                                           __ATOMIC_RELAXED, __HIP_MEMORY_SCOPE_AGENT);
            if (m == 7) {
#pragma unroll
                for (int i = 0; i < 8; i++)
                    __hip_atomic_store(wsi + RELo + i * 32, idx + 1,
                                       __ATOMIC_RELAXED, __HIP_MEMORY_SCOPE_AGENT);
                bcast = true;
            }
        }
        if (!bcast) {
            const int* myrel = wsi + RELo + leaf * 32;
            while (__hip_atomic_load(myrel, __ATOMIC_RELAXED, __HIP_MEMORY_SCOPE_AGENT) <= idx)
                __builtin_amdgcn_s_sleep(4);
        }
    }
    __syncthreads();
}

__global__ __launch_bounds__(1024, 1) void k_fused(
        const float* __restrict__ x,
        const float* __restrict__ Wq, const float* __restrict__ bq,
        const float* __restrict__ Wk, const float* __restrict__ bk,
        const float* __restrict__ wcq, const float* __restrict__ wck,
        const float* __restrict__ Wv, const float* __restrict__ bv,
        const float* __restrict__ Wg, const float* __restrict__ bg,
        float* __restrict__ ws, float* __restrict__ out) {
    __shared__ float smem[13824];       // 55.3 KB
    int tid = threadIdx.x;
    int bid = blockIdx.x;
    int b = bid >> 6, t6 = bid & 63;
    int* wsi = (int*)ws;
    int* gh  = wsi + GHo;

    float myA = 0.f;                    // a for pixel t6*64+tid (tid<64)

    // ===== Phase A: weight prep (redundant) + projections + histogram =====
    {
        float* xt  = smem;              // [64][72]
        float* wt  = smem + 4608;       // [64][72]: wt[c][o] = Wvg[o][c]
        float* wqe = smem + 9216, *wke = smem + 9280, *bvg = smem + 9344, *misc = smem + 9408;
        if (tid < 64) {
            float s1 = 0.f, s2 = 0.f, s3 = 0.f;
            for (int o = 0; o < 16; o++) { s1 += wcq[o] * Wq[o * 64 + tid]; s2 += wck[o] * Wk[o * 64 + tid]; }
            for (int m = 0; m < 64; m++) s3 += Wg[tid * 64 + m] * bv[m];
            wqe[tid] = s1; wke[tid] = s2; bvg[tid] = s3;
        } else if (tid == 64) {
            float s = 0.f; for (int o = 0; o < 16; o++) s += wcq[o] * bq[o]; misc[0] = s;
        } else if (tid == 65) {
            float s = 0.f; for (int o = 0; o < 16; o++) s += wck[o] * bk[o]; misc[1] = s;
        }
        {
            // Wvg: each thread 4 outputs (o = tid&63, c0 = (tid>>6)*4)
            int o = tid & 63, c0 = (tid >> 6) * 4;
            float a0 = 0.f, a1 = 0.f, a2 = 0.f, a3 = 0.f;
            for (int m = 0; m < 64; m++) {
                float wg = Wg[o * 64 + m];
                const float4 wv4 = *(const float4*)(Wv + m * 64 + c0);   // wave-broadcast
                a0 += wg * wv4.x; a1 += wg * wv4.y; a2 += wg * wv4.z; a3 += wg * wv4.w;
            }
            wt[(c0 + 0) * 72 + o] = a0; wt[(c0 + 1) * 72 + o] = a1;
            wt[(c0 + 2) * 72 + o] = a2; wt[(c0 + 3) * 72 + o] = a3;
        }
        {
            const float4* xb4 = (const float4*)(x + (size_t)b * 64 * 4096);
            int c = tid >> 4, nl4 = tid & 15;
            *(float4*)&xt[c * 72 + nl4 * 4] = xb4[c * 1024 + t6 * 16 + nl4];
        }
        __syncthreads();
        if (tid < 64) {
            float s1 = misc[0], s2 = misc[1];
            for (int c = 0; c < 64; c++) {
                float xv = xt[c * 72 + tid];
                s1 += wqe[c] * xv; s2 += wke[c] * xv;
            }
            myA = s1;
            ws[Do + b * 4096 + t6 * 64 + tid] = s2;        // block-local (F)
            atomicAdd(&gh[b * 4096 + bucket_of(s1)], 1);   // device-scope -> MALL
        }
        {
            // VG: each thread 4 outputs (o = tid&63, nl0 = (tid>>6)*4)
            int o = tid & 63, nl0 = (tid >> 6) * 4;
            float bo = bvg[o];
            float a0 = bo, a1 = bo, a2 = bo, a3 = bo;
            for (int c = 0; c < 64; c++) {
                float wv = wt[c * 72 + o];
                const float* xr = &xt[c * 72 + nl0];
                a0 += wv * xr[0]; a1 += wv * xr[1]; a2 += wv * xr[2]; a3 += wv * xr[3];
            }
            size_t base = ((size_t)(b * 4096) + t6 * 64 + nl0) * 64 + o;
            gst(&ws[VGo + base], a0);
            gst(&ws[VGo + base + 64], a1);
            gst(&ws[VGo + base + 128], a2);
            gst(&ws[VGo + base + 192], a3);
        }
    }
    gbar(wsi, 0);

    // ===== Phase B: per-block shfl scan (4 buckets/thread) + scatter =====
    {
        unsigned int* hist = (unsigned int*)smem;          // [4096]
        unsigned int* wtot = hist + 4096;                  // [16]
        const int* gh_b = gh + b * 4096;
        int* gcnt = wsi + GCNTo + b * 4096;
#pragma unroll
        for (int i = tid; i < NB; i += 1024) hist[i] = (unsigned int)gh_b[i];  // cached first-touch
        __syncthreads();
        int lane = tid & 63, w = tid >> 6;
        int base = tid * 4;
        unsigned int h0 = hist[base], h1 = hist[base + 1], h2 = hist[base + 2], h3 = hist[base + 3];
        unsigned int s = h0 + h1 + h2 + h3;
        unsigned int inc = s;
        for (int off = 1; off < 64; off <<= 1) {
            unsigned int u = __shfl_up(inc, off);
            if (lane >= off) inc += u;
        }
        if (lane == 63) wtot[w] = inc;
        __syncthreads();
        unsigned int run = inc - s;
        for (int w2 = 0; w2 < w; w2++) run += wtot[w2];
        hist[base] = run; run += h0;
        hist[base + 1] = run; run += h1;
        hist[base + 2] = run; run += h2;
        hist[base + 3] = run;
        __syncthreads();
        if (t6 == 0) {                   // publish bst once per batch (for F)
            int* bst = wsi + BSTo;
#pragma unroll
            for (int i = tid; i < NB; i += 1024) gsti(&bst[b * 4096 + i], (int)hist[i]);
        }
        if (tid < 64) {                  // scatter own pixel (a in register)
            int i = t6 * 64 + tid;
            int kb = bucket_of(myA);
            int r = (int)hist[kb] + atomicAdd(&gcnt[kb], 1);
            gst(&ws[ASo + b * 4096 + r], myA);
            gsti((int*)ws + PERMo + b * 4096 + r, i);
        }
    }
    gbar(wsi, 1);

    // ===== Phase C: chunk partials, 4 ranks/thread =====
    {
        int c = tid & 63, seg = tid >> 6;       // 16 segs x 4 ranks
        int r0 = t6 * 64 + seg * 4;
        const int* perm = (const int*)ws + PERMo;
        int pk[4]; float avs[4], wvs[4];
#pragma unroll
        for (int k = 0; k < 4; k++) pk[k] = perm[b * 4096 + r0 + k];
#pragma unroll
        for (int k = 0; k < 4; k++) avs[k] = ws[ASo + b * 4096 + r0 + k];
#pragma unroll
        for (int k = 0; k < 4; k++) wvs[k] = ws[VGo + ((size_t)(b * 4096) + pk[k]) * 64 + c];
        float s1 = 0.f, s2 = 0.f, s3 = 0.f, sea_w = 0.f, sa_w = 0.f;
#pragma unroll
        for (int k = 0; k < 4; k++) {
            float ea = expf(avs[k]);
            s1 += wvs[k]; s2 += wvs[k] * ea; s3 += wvs[k] * avs[k];
            sea_w += ea; sa_w += avs[k];
        }
        float* partL = smem;            // [16][3][64] = 3072
        float* wsc   = smem + 3072;     // [32]
        partL[(seg * 3 + 0) * 64 + c] = s1;
        partL[(seg * 3 + 1) * 64 + c] = s2;
        partL[(seg * 3 + 2) * 64 + c] = s3;
        if (c == 0) { wsc[seg] = sea_w; wsc[16 + seg] = sa_w; }
        __syncthreads();
        if (tid < 192) {
            int g = tid >> 6, cc = tid & 63;
            float s = 0.f;
#pragma unroll
            for (int sg = 0; sg < 16; sg++) s += partL[(sg * 3 + g) * 64 + cc];
            gst(&ws[Po + (b * 64 + t6) * 192 + tid], s);
        } else if (tid == 192) {
            float s = 0.f;
#pragma unroll
            for (int sg = 0; sg < 16; sg++) s += wsc[sg];
            gst(&ws[PSEAo + b * 64 + t6], s);
        } else if (tid == 193) {
            float s = 0.f;
#pragma unroll
            for (int sg = 0; sg < 16; sg++) s += wsc[16 + sg];
            gst(&ws[PSAo + b * 64 + t6], s);
        }
    }
    gbar(wsi, 2);

    // ===== Phase F: 2-level chunk-prefix scan + output =====
    {
        float* CP     = smem;                   // [65][193] = 12545
        float* segtot = smem + 12545;           // [4][192]
        float* scseg  = smem + 13313;           // [8]
        float* cpsea  = smem + 13321;           // [65]
        float* cpsa   = smem + 13386;           // [65]
        float* djs    = smem + 13451;           // [64]
        float* edjs   = smem + 13515;           // [64]
        float* invden = smem + 13579;           // [64]
        int*   qarr   = (int*)(smem + 13643);   // [64]
        float* bgs    = smem + 13707;           // [64]
        float v[16]; int col = 0, seg = 0;
        // stage 1: segment sums
        if (tid < 768) {
            col = tid % 192; seg = tid / 192;
            float s = 0.f;
#pragma unroll
            for (int u = 0; u < 16; u++) {
                v[u] = ws[Po + b * 12288 + (seg * 16 + u) * 192 + col];  // cached
                s += v[u];
            }
            segtot[seg * 192 + col] = s;
        } else if (tid < 776) {
            int idx = tid - 768; int which = idx & 1; seg = idx >> 1;
            const float* src = which ? &ws[PSAo + b * 64] : &ws[PSEAo + b * 64];
            float s = 0.f;
#pragma unroll
            for (int u = 0; u < 16; u++) { v[u] = src[seg * 16 + u]; s += v[u]; }
            scseg[which * 4 + seg] = s;
        } else if (tid < 840) {
            bgs[tid - 776] = bg[tid - 776];
        }
        __syncthreads();
        // stage 2: exclusive prefix write
        if (tid < 768) {
            float r = 0.f;
            for (int s2 = 0; s2 < seg; s2++) r += segtot[s2 * 192 + col];
#pragma unroll
            for (int u = 0; u < 16; u++) {
                CP[(seg * 16 + u) * 193 + col] = r;
                r += v[u];
            }
            if (seg == 3) CP[64 * 193 + col] = r;
        } else if (tid < 776) {
            int idx = tid - 768; int which = idx & 1; seg = idx >> 1;
            float* dst = which ? cpsa : cpsea;
            float r = 0.f;
            for (int s2 = 0; s2 < seg; s2++) r += scseg[which * 4 + s2];
#pragma unroll
            for (int u = 0; u < 16; u++) { dst[seg * 16 + u] = r; r += v[u]; }
            if (seg == 3) dst[64] = r;
        }
        __syncthreads();
        const int* bst = (const int*)ws + BSTo;
        int j0 = t6 * 64;
        if (tid < 64) {
            int j = j0 + tid;
            float dj = ws[Do + b * 4096 + j];
            float edj = expf(dj);
            int kb = bucket_of(-dj);
            int t = bst[b * NB + kb];          // cached first-touch
            int q = (t + 32) >> 6;             // snap to chunk boundary
            float den = 1.5f * ((cpsa[64] - cpsa[q]) + dj * (float)(4096 - 64 * q)
                                - (float)(64 * q) + edj * cpsea[q]);
            qarr[tid] = q; djs[tid] = dj; edjs[tid] = edj; invden[tid] = 1.0f / den;
        }
        __syncthreads();
        {
            int jl = tid & 63, cq = tid >> 6;
            float dj = djs[jl], edj = edjs[jl], inv = invden[jl];
            int qb = qarr[jl] * 193;
#pragma unroll
            for (int cc = cq; cc < 64; cc += 16) {
                float c1 = CP[qb + cc], c2 = CP[qb + 64 + cc], c3 = CP[qb + 128 + cc];
                float t1 = CP[64 * 193 + cc], t3 = CP[64 * 193 + 128 + cc];
                float num = (t3 - c3) + dj * t1 - (1.0f + dj) * c1 + edj * c2;
                out[((size_t)(b * 64 + cc)) * 4096 + j0 + jl] = num * inv + bgs[cc];
            }
        }
    }
}

extern "C" void kernel_launch(void* const* d_in, const int* in_sizes, int n_in,
                              void* d_out, int out_size, void* d_ws, size_t ws_size,
                              hipStream_t stream) {
    const float* x   = (const float*)d_in[0];
    const float* Wq  = (const float*)d_in[1];
    const float* bq  = (const float*)d_in[2];
    const float* Wk  = (const float*)d_in[3];
    const float* bk  = (const float*)d_in[4];
    const float* wcq = (const float*)d_in[5];
    const float* wck = (const float*)d_in[6];
    const float* Wv  = (const float*)d_in[7];
    const float* bv  = (const float*)d_in[8];
    const float* Wg  = (const float*)d_in[9];
    const float* bg  = (const float*)d_in[10];
    float* ws  = (float*)d_ws;
    float* out = (float*)d_out;

    hipMemsetAsync(d_ws, 0, MEMSET_BYTES, stream);
    k_fused<<<256, 1024, 0, stream>>>(x, Wq, bq, Wk, bk, wcq, wck, Wv, bv, Wg, bg, ws, out);
}

// Round 11
// 102.834 us; speedup vs baseline: 1.0666x; 1.0666x over previous
//
#include <hip/hip_runtime.h>
#include <math.h>

#define NB 4096

// ---- workspace layout ----
// ints:
#define LEAFo  0               // 3 barriers * 8 leaves * 32 ints (128B spacing)
#define MASTo  768             // 3 * 32
#define RELo   864             // 8 * 32 spread release lines
#define GHo    1120            // 4*4096 histogram (low 16b: count, high 16b: scatter cursor)
#define MEMSET_BYTES 70016     // 17504 ints
// floats:
#define VGo    17504           // B*4096*64
#define ASo    1066080         // sorted a
#define PERMo  1082464         // int
#define Po     1098848         // chunk partials [b][64ch][192]
#define PSEAo  1148000         // [b][64]
#define PSAo   1148256         // [b][64]

__device__ __forceinline__ void gst(float* p, float v) {
    __hip_atomic_store(p, v, __ATOMIC_RELAXED, __HIP_MEMORY_SCOPE_AGENT);
}
__device__ __forceinline__ void gsti(int* p, int v) {
    __hip_atomic_store(p, v, __ATOMIC_RELAXED, __HIP_MEMORY_SCOPE_AGENT);
}

__device__ __forceinline__ int bucket_of(float v) {
    int k = (int)((v + 16.0f) * 128.0f);
    k = k < 0 ? 0 : k;
    k = k > (NB - 1) ? (NB - 1) : k;
    return k;
}

// Tree-arrival barrier (validated R9): 32 contenders/leaf, 8 leaves/master,
// release on 8 spread lines.
__device__ __forceinline__ void gbar(int* wsi, int idx) {
    __syncthreads();
    if (threadIdx.x == 0) {
        int leaf = blockIdx.x & 7;
        bool bcast = false;
        int old = __hip_atomic_fetch_add(wsi + LEAFo + (idx * 8 + leaf) * 32, 1,
                                         __ATOMIC_RELAXED, __HIP_MEMORY_SCOPE_AGENT);
        if (old == 31) {
            int m = __hip_atomic_fetch_add(wsi + MASTo + idx * 32, 1,
                                           __ATOMIC_RELAXED, __HIP_MEMORY_SCOPE_AGENT);
            if (m == 7) {
#pragma unroll
                for (int i = 0; i < 8; i++)
                    __hip_atomic_store(wsi + RELo + i * 32, idx + 1,
                                       __ATOMIC_RELAXED, __HIP_MEMORY_SCOPE_AGENT);
                bcast = true;
            }
        }
        if (!bcast) {
            const int* myrel = wsi + RELo + leaf * 32;
            while (__hip_atomic_load(myrel, __ATOMIC_RELAXED, __HIP_MEMORY_SCOPE_AGENT) <= idx)
                __builtin_amdgcn_s_sleep(1);
        }
    }
    __syncthreads();
}

__global__ __launch_bounds__(256, 1) void k_fused(
        const float* __restrict__ x,
        const float* __restrict__ Wq, const float* __restrict__ bq,
        const float* __restrict__ Wk, const float* __restrict__ bk,
        const float* __restrict__ wcq, const float* __restrict__ wck,
        const float* __restrict__ Wv, const float* __restrict__ bv,
        const float* __restrict__ Wg, const float* __restrict__ bg,
        float* __restrict__ ws, float* __restrict__ out) {
    __shared__ float smem[13824];       // 55.3 KB
    int tid = threadIdx.x;
    int bid = blockIdx.x;
    int b = bid >> 6, t6 = bid & 63;
    int* wsi = (int*)ws;

    float myA = 0.f, myD = 0.f;         // a,d for pixel t6*64+tid (tid<64)
    int   myQ = 0;                      // snapped split chunk for own column j

    // ===== Phase A: weight prep (redundant) + projections + histogram =====
    {
        float* xt  = smem;              // [64][72] = 4608
        float* wt  = smem + 4608;       // [64][72]: wt[c][o] = Wvg[o][c]
        float* wgT = smem + 9216;       // [64][64]: wgT[m][o] = Wg[o][m]
        float* wqe = smem + 13312, *wke = smem + 13376, *bvg = smem + 13440, *misc = smem + 13504;
        // 1) x tile prefetch into registers (HBM latency overlaps Wg/Wvg work)
        const float4* xb4 = (const float4*)(x + (size_t)b * 64 * 4096);
        float4 xr[4];
#pragma unroll
        for (int k = 0; k < 4; k++) {
            int idx = tid + k * 256, c = idx >> 4, nl4 = idx & 15;
            xr[k] = xb4[c * 1024 + t6 * 16 + nl4];
        }
        // 2) stage Wg transposed into LDS (coalesced global read)
        {
            const float4* wg4 = (const float4*)Wg;
            int o = tid >> 2;
#pragma unroll
            for (int k4 = 0; k4 < 4; k4++) {
                float4 g = wg4[tid * 4 + k4];
                int m0 = (tid & 3) * 16 + k4 * 4;
                wgT[(m0 + 0) * 64 + o] = g.x; wgT[(m0 + 1) * 64 + o] = g.y;
                wgT[(m0 + 2) * 64 + o] = g.z; wgT[(m0 + 3) * 64 + o] = g.w;
            }
        }
        if (tid < 64) {
            float s1 = 0.f, s2 = 0.f, s3 = 0.f;
            for (int o = 0; o < 16; o++) { s1 += wcq[o] * Wq[o * 64 + tid]; s2 += wck[o] * Wk[o * 64 + tid]; }
            for (int m = 0; m < 64; m++) s3 += Wg[tid * 64 + m] * bv[m];
            wqe[tid] = s1; wke[tid] = s2; bvg[tid] = s3;
        } else if (tid == 64) {
            float s = 0.f; for (int o = 0; o < 16; o++) s += wcq[o] * bq[o]; misc[0] = s;
        } else if (tid == 65) {
            float s = 0.f; for (int o = 0; o < 16; o++) s += wck[o] * bk[o]; misc[1] = s;
        }
        // 3) store x tile to LDS
#pragma unroll
        for (int k = 0; k < 4; k++) {
            int idx = tid + k * 256, c = idx >> 4, nl4 = idx & 15;
            *(float4*)&xt[c * 72 + nl4 * 4] = xr[k];
        }
        __syncthreads();
        // 4) Wvg = Wg @ Wv from LDS-transposed Wg (conflict-free) + Wv broadcast
        {
            int o = tid & 63, c0 = (tid >> 6) * 16;
            float acc[16];
#pragma unroll
            for (int k = 0; k < 16; k++) acc[k] = 0.f;
            for (int m = 0; m < 64; m++) {
                float wg = wgT[m * 64 + o];
                const float4* wv4 = (const float4*)(Wv + m * 64 + c0);
                float4 a0 = wv4[0], a1 = wv4[1], a2 = wv4[2], a3 = wv4[3];
                acc[0] += wg * a0.x; acc[1] += wg * a0.y; acc[2] += wg * a0.z; acc[3] += wg * a0.w;
                acc[4] += wg * a1.x; acc[5] += wg * a1.y; acc[6] += wg * a1.z; acc[7] += wg * a1.w;
                acc[8] += wg * a2.x; acc[9] += wg * a2.y; acc[10] += wg * a2.z; acc[11] += wg * a2.w;
                acc[12] += wg * a3.x; acc[13] += wg * a3.y; acc[14] += wg * a3.z; acc[15] += wg * a3.w;
            }
#pragma unroll
            for (int k = 0; k < 16; k++) wt[(c0 + k) * 72 + o] = acc[k];
        }
        __syncthreads();
        if (tid < 64) {
            float s1 = misc[0], s2 = misc[1];
            for (int c = 0; c < 64; c++) {
                float xv = xt[c * 72 + tid];
                s1 += wqe[c] * xv; s2 += wke[c] * xv;
            }
            myA = s1; myD = s2;                              // both stay in registers
            atomicAdd(&wsi[GHo + b * 4096 + bucket_of(s1)], 1);
        }
        {
            int o = tid & 63, nl0 = (tid >> 6) * 16;
            float acc[16];
            float bo = bvg[o];
#pragma unroll
            for (int k = 0; k < 16; k++) acc[k] = bo;
            for (int c = 0; c < 64; c++) {
                float wv = wt[c * 72 + o];
                const float* xr2 = &xt[c * 72 + nl0];
#pragma unroll
                for (int k = 0; k < 16; k++) acc[k] += wv * xr2[k];
            }
#pragma unroll
            for (int k = 0; k < 16; k++)
                gst(&ws[VGo + ((size_t)(b * 4096) + t6 * 64 + nl0 + k) * 64 + o], acc[k]);
        }
    }
    gbar(wsi, 0);

    // ===== Phase B: per-block shfl scan + scatter + own-column split lookup =====
    {
        unsigned int* hist = (unsigned int*)smem;          // [4096] bucket starts
        unsigned int* wtot = hist + 4096;                  // [4]
        int* gh_b = wsi + GHo + b * 4096;
#pragma unroll 4
        for (int i = tid; i < NB; i += 256) hist[i] = (unsigned int)gh_b[i] & 0xFFFFu;  // cached
        __syncthreads();
        int lane = tid & 63, w = tid >> 6;
        unsigned int s = 0u; int base = tid * 16;
#pragma unroll
        for (int k = 0; k < 16; k++) s += hist[base + k];
        unsigned int inc = s;
        for (int off = 1; off < 64; off <<= 1) {
            unsigned int u = __shfl_up(inc, off);
            if (lane >= off) inc += u;
        }
        if (lane == 63) wtot[w] = inc;
        __syncthreads();
        unsigned int run = inc - s;
        for (int w2 = 0; w2 < w; w2++) run += wtot[w2];
        for (int k = 0; k < 16; k++) {
            unsigned int h = hist[base + k];
            hist[base + k] = run;       // hist now holds bucket starts
            run += h;
        }
        __syncthreads();
        if (tid < 64) {
            // split lookup for own output column j = t6*64+tid (d in register)
            myQ = ((int)hist[bucket_of(-myD)] + 32) >> 6;
            // scatter own pixel; cursor packed in GH high bits
            int i = t6 * 64 + tid;
            int kb = bucket_of(myA);
            int old = atomicAdd(&gh_b[kb], 0x10000);
            int r = (int)hist[kb] + (old >> 16);
            gst(&ws[ASo + b * 4096 + r], myA);
            gsti((int*)ws + PERMo + b * 4096 + r, i);
        }
    }
    gbar(wsi, 1);

    // ===== Phase C: chunk partials (cached reads, sc writes) =====
    {
        int c = tid & 63, w = tid >> 6;
        int r0 = t6 * 64 + w * 16;
        const int* perm = (const int*)ws + PERMo;
        int pk[16]; float avs[16], wvs[16];
#pragma unroll
        for (int k = 0; k < 16; k++) pk[k] = perm[b * 4096 + r0 + k];
#pragma unroll
        for (int k = 0; k < 16; k++) avs[k] = ws[ASo + b * 4096 + r0 + k];
#pragma unroll
        for (int k = 0; k < 16; k++) wvs[k] = ws[VGo + ((size_t)(b * 4096) + pk[k]) * 64 + c];
        float s1 = 0.f, s2 = 0.f, s3 = 0.f, sea_w = 0.f, sa_w = 0.f;
#pragma unroll
        for (int k = 0; k < 16; k++) {
            float ea = expf(avs[k]);
            s1 += wvs[k]; s2 += wvs[k] * ea; s3 += wvs[k] * avs[k];
            sea_w += ea; sa_w += avs[k];
        }
        float* partL = smem;            // [4][3][64]
        float* wsc   = smem + 768;      // [8]
        partL[(w * 3 + 0) * 64 + c] = s1;
        partL[(w * 3 + 1) * 64 + c] = s2;
        partL[(w * 3 + 2) * 64 + c] = s3;
        if (c == 0) { wsc[w] = sea_w; wsc[4 + w] = sa_w; }
        __syncthreads();
        if (tid < 192) {
            int g = tid >> 6, cc = tid & 63;
            float s = partL[(0 * 3 + g) * 64 + cc] + partL[(1 * 3 + g) * 64 + cc]
                    + partL[(2 * 3 + g) * 64 + cc] + partL[(3 * 3 + g) * 64 + cc];
            gst(&ws[Po + (b * 64 + t6) * 192 + tid], s);
        } else if (tid == 192) {
            gst(&ws[PSEAo + b * 64 + t6], wsc[0] + wsc[1] + wsc[2] + wsc[3]);
        } else if (tid == 193) {
            gst(&ws[PSAo + b * 64 + t6], wsc[4] + wsc[5] + wsc[6] + wsc[7]);
        }
    }
    gbar(wsi, 2);

    // ===== Phase F: per-block chunk-prefix (reg prefetch) + output =====
    {
        float* CP     = smem;                  // [65][193] = 12545
        float* cpsea  = smem + 12545;          // [65]
        float* cpsa   = smem + 12610;          // [65]
        float* djs    = smem + 12675;          // [64]
        float* edjs   = smem + 12739;          // [64]
        float* invden = smem + 12803;          // [64]
        int*   qarr   = (int*)(smem + 12867);  // [64]
        float* bgs    = smem + 12931;          // [64]
        if (tid < 192) {
            float v[64];
#pragma unroll
            for (int ch = 0; ch < 64; ch++) v[ch] = ws[Po + b * 12288 + ch * 192 + tid]; // cached
            float r = 0.f;
#pragma unroll
            for (int q = 0; q < 64; q++) { CP[q * 193 + tid] = r; r += v[q]; }
            CP[64 * 193 + tid] = r;
        } else if (tid == 192) {
            float v[64];
#pragma unroll
            for (int ch = 0; ch < 64; ch++) v[ch] = ws[PSEAo + b * 64 + ch];
            float r = 0.f;
#pragma unroll
            for (int q = 0; q < 64; q++) { cpsea[q] = r; r += v[q]; }
            cpsea[64] = r;
        } else if (tid == 193) {
            float v[64];
#pragma unroll
            for (int ch = 0; ch < 64; ch++) v[ch] = ws[PSAo + b * 64 + ch];
            float r = 0.f;
#pragma unroll
            for (int q = 0; q < 64; q++) { cpsa[q] = r; r += v[q]; }
            cpsa[64] = r;
        }
        if (tid < 64) bgs[tid] = bg[tid];
        __syncthreads();
        int j0 = t6 * 64;
        if (tid < 64) {
            float dj = myD;
            float edj = expf(dj);
            int q = myQ;
            float den = 1.5f * ((cpsa[64] - cpsa[q]) + dj * (float)(4096 - 64 * q)
                                - (float)(64 * q) + edj * cpsea[q]);
            qarr[tid] = q; djs[tid] = dj; edjs[tid] = edj; invden[tid] = 1.0f / den;
        }
        __syncthreads();
        {
            int jl = tid & 63, cq = tid >> 6;
            float dj = djs[jl], edj = edjs[jl], inv = invden[jl];
            int qb = qarr[jl] * 193;
            for (int cc = cq; cc < 64; cc += 4) {
                float c1 = CP[qb + cc], c2 = CP[qb + 64 + cc], c3 = CP[qb + 128 + cc];
                float t1 = CP[64 * 193 + cc], t3 = CP[64 * 193 + 128 + cc];
                float num = (t3 - c3) + dj * t1 - (1.0f + dj) * c1 + edj * c2;
                out[((size_t)(b * 64 + cc)) * 4096 + j0 + jl] = num * inv + bgs[cc];
            }
        }
    }
}

extern "C" void kernel_launch(void* const* d_in, const int* in_sizes, int n_in,
                              void* d_out, int out_size, void* d_ws, size_t ws_size,
                              hipStream_t stream) {
    const float* x   = (const float*)d_in[0];
    const float* Wq  = (const float*)d_in[1];
    const float* bq  = (const float*)d_in[2];
    const float* Wk  = (const float*)d_in[3];
    const float* bk  = (const float*)d_in[4];
    const float* wcq = (const float*)d_in[5];
    const float* wck = (const float*)d_in[6];
    const float* Wv  = (const float*)d_in[7];
    const float* bv  = (const float*)d_in[8];
    const float* Wg  = (const float*)d_in[9];
    const float* bg  = (const float*)d_in[10];
    float* ws  = (float*)d_ws;
    float* out = (float*)d_out;

    hipMemsetAsync(d_ws, 0, MEMSET_BYTES, stream);
    k_fused<<<256, 256, 0, stream>>>(x, Wq, bq, Wk, bk, wcq, wck, Wv, bv, Wg, bg, ws, out);
}